// Round 5
// baseline (419.051 us; speedup 1.0000x reference)
//
#include <hip/hip_runtime.h>
#include <stdint.h>

#define NSEQ 512
#define DDIM 128
#define NROWS (NSEQ * NSEQ)   // 262144

typedef __bf16 bf16x8 __attribute__((ext_vector_type(8)));
typedef unsigned short u16;
typedef u16 ushort8 __attribute__((ext_vector_type(8)));
typedef float f32x4 __attribute__((ext_vector_type(4)));
typedef uint32_t u32x4 __attribute__((ext_vector_type(4)));
typedef uint32_t u32x2 __attribute__((ext_vector_type(2)));

__device__ __forceinline__ u16 f2bf(float f) {
  uint32_t x = __builtin_bit_cast(uint32_t, f);
  x += 0x7fffu + ((x >> 16) & 1u);   // round-to-nearest-even
  return (u16)(x >> 16);
}
__device__ __forceinline__ float bf2f(u16 u) {
  uint32_t x = ((uint32_t)u) << 16;
  return __builtin_bit_cast(float, x);
}
__device__ __forceinline__ f32x4 mfma_bf16(ushort8 a, ushort8 b, f32x4 c) {
  return __builtin_amdgcn_mfma_f32_16x16x32_bf16(
      __builtin_bit_cast(bf16x8, a), __builtin_bit_cast(bf16x8, b), c, 0, 0, 0);
}
__device__ __forceinline__ float sigmoidf_(float x) {
  return 1.0f / (1.0f + __expf(-x));
}

#define GLOAD16(gp, lp)                                                        \
  __builtin_amdgcn_global_load_lds(                                            \
      (const __attribute__((address_space(1))) void*)(gp),                     \
      (__attribute__((address_space(3))) void*)(lp), 16, 0, 0)

// ---------------------------------------------------------------------------
// K0: weight prep (unchanged).
// ---------------------------------------------------------------------------
__global__ void k0_prep(const float* __restrict__ p_in_w,
                        const float* __restrict__ g_in_w,
                        const float* __restrict__ p_out_w,
                        const float* __restrict__ g_out_w,
                        const float* __restrict__ now,
                        const float* __restrict__ nob,
                        u16* __restrict__ Wb, u16* __restrict__ Pb,
                        u16* __restrict__ Gb, float* __restrict__ S12) {
  const int t = threadIdx.x;  // 256 threads, 1 block
  for (int idx = t; idx < 512 * 128; idx += 256) {
    const int e = idx >> 7, d = idx & 127;
    const float v = (e < 256) ? p_in_w[e * 128 + d] : g_in_w[(e - 256) * 128 + d];
    Wb[idx] = f2bf(v);
  }
  for (int idx = t; idx < 128 * 128; idx += 256) {
    const int d = idx & 127;
    Pb[idx] = f2bf(p_out_w[idx] * now[d]);
    Gb[idx] = f2bf(g_out_w[idx]);
  }
  if (t < 128) {
    float s1 = 0.f, s2 = 0.f;
    for (int d = 0; d < 128; ++d) {
      s1 += p_out_w[t * 128 + d] * now[d];
      s2 += p_out_w[t * 128 + d] * nob[d];
    }
    S12[2 * t] = s1;
    S12[2 * t + 1] = s2;
  }
}

// ---------------------------------------------------------------------------
// K1: LN(x) -> h = (xln @ p_in^T) * sigmoid(xln @ g_in^T) * mask -> At/Bt.
// Pass 2 (gArg != nullptr): gArg[r][e] = xln @ g_out^T (round-3 verified MFMA
// layout), with the 2B global scatter replaced by an LDS-staged transpose +
// coalesced 16B stores.
// ---------------------------------------------------------------------------
__global__ __launch_bounds__(256, 4) void k1_ln_proj(
    const float* __restrict__ x, const float* __restrict__ mask,
    const float* __restrict__ niw, const float* __restrict__ nib,
    const u16* __restrict__ Wb, const u16* __restrict__ Gb,
    u16* __restrict__ At, u16* __restrict__ Bt, u16* __restrict__ gArg) {
  __shared__ __align__(16) u16 xln[64 * 128];    // LN rows, 16B-granule XOR swizzle
  __shared__ __align__(16) u16 stage[128 * 64];  // [d][r], 8B-granule XOR swizzle
  __shared__ __align__(16) u16 stage2[64 * 64];  // [r][e_loc], 8B-granule XOR swizzle
  const int tid = threadIdx.x;
  const int lane = tid & 63;
  const int w = tid >> 6;
  const int bid = blockIdx.x;
  const int rb = (bid >> 4) * 8 + (bid & 7);
  const int cg = (bid >> 3) & 1;
  const int r0 = rb * 64;
  const int g = lane >> 4, c = lane & 15;

  // --- LN phase ---
  f32x4 v0[4], v1[4];
#pragma unroll
  for (int it = 0; it < 4; ++it) {
    const int rl = w * 16 + it * 4 + g;
    const float* xr = x + (size_t)(r0 + rl) * DDIM + c * 8;
    v0[it] = *(const f32x4*)xr;
    v1[it] = *(const f32x4*)(xr + 4);
  }
  const f32x4 w0 = *(const f32x4*)(niw + c * 8);
  const f32x4 w1 = *(const f32x4*)(niw + c * 8 + 4);
  const f32x4 b0 = *(const f32x4*)(nib + c * 8);
  const f32x4 b1 = *(const f32x4*)(nib + c * 8 + 4);
#pragma unroll
  for (int it = 0; it < 4; ++it) {
    const int rl = w * 16 + it * 4 + g;
    float s = v0[it][0] + v0[it][1] + v0[it][2] + v0[it][3] +
              v1[it][0] + v1[it][1] + v1[it][2] + v1[it][3];
    float ss = v0[it][0] * v0[it][0] + v0[it][1] * v0[it][1] +
               v0[it][2] * v0[it][2] + v0[it][3] * v0[it][3] +
               v1[it][0] * v1[it][0] + v1[it][1] * v1[it][1] +
               v1[it][2] * v1[it][2] + v1[it][3] * v1[it][3];
#pragma unroll
    for (int m = 1; m < 16; m <<= 1) {
      s += __shfl_xor(s, m);
      ss += __shfl_xor(ss, m);
    }
    const float mu = s * (1.0f / 128.0f);
    const float rs = rsqrtf(ss * (1.0f / 128.0f) - mu * mu + 1e-5f);
    ushort8 o;
#pragma unroll
    for (int j = 0; j < 4; ++j) o[j] = f2bf((v0[it][j] - mu) * rs * w0[j] + b0[j]);
#pragma unroll
    for (int j = 0; j < 4; ++j) o[4 + j] = f2bf((v1[it][j] - mu) * rs * w1[j] + b1[j]);
    const int byteoff = rl * 256 + ((c ^ (rl & 7)) << 4);
    *(ushort8*)((char*)xln + byteoff) = o;
  }
  __syncthreads();

  // --- MFMA pass 1: P-cols + gate-in cols ---
  const int lr = lane & 15, lq = lane >> 4;
  const int eP = cg * 128 + w * 32;
  f32x4 accP[4][2], accG[4][2];
#pragma unroll
  for (int m = 0; m < 4; ++m)
#pragma unroll
    for (int n = 0; n < 2; ++n) {
      accP[m][n] = f32x4{0.f, 0.f, 0.f, 0.f};
      accG[m][n] = f32x4{0.f, 0.f, 0.f, 0.f};
    }

#pragma unroll
  for (int ks = 0; ks < 4; ++ks) {
    const int kblk = ks * 4 + lq;
    ushort8 af[4];
#pragma unroll
    for (int m = 0; m < 4; ++m) {
      const int row = m * 16 + lr;
      af[m] = *(const ushort8*)((const char*)xln + row * 256 +
                                ((kblk ^ (row & 7)) << 4));
    }
    ushort8 bP[2], bG[2];
#pragma unroll
    for (int n = 0; n < 2; ++n) {
      const int e = eP + n * 16 + lr;
      const int dd = ks * 32 + lq * 8;
      bP[n] = *(const ushort8*)(Wb + e * 128 + dd);
      bG[n] = *(const ushort8*)(Wb + (256 + e) * 128 + dd);
    }
#pragma unroll
    for (int m = 0; m < 4; ++m)
#pragma unroll
      for (int n = 0; n < 2; ++n) {
        accP[m][n] = mfma_bf16(af[m], bP[n], accP[m][n]);
        accG[m][n] = mfma_bf16(af[m], bG[n], accG[m][n]);
      }
  }

  // --- epilogue: gate + mask -> swizzled LDS stage [d][r] ---
#pragma unroll
  for (int m = 0; m < 4; ++m) {
    const int rloc = m * 16 + lq * 4;
    const f32x4 mv = *(const f32x4*)(mask + r0 + rloc);
#pragma unroll
    for (int n = 0; n < 2; ++n) {
      const int d = w * 32 + n * 16 + lr;   // col within At/Bt [0,128)
      const float o0 = accP[m][n][0] * sigmoidf_(accG[m][n][0]) * mv[0];
      const float o1 = accP[m][n][1] * sigmoidf_(accG[m][n][1]) * mv[1];
      const float o2 = accP[m][n][2] * sigmoidf_(accG[m][n][2]) * mv[2];
      const float o3 = accP[m][n][3] * sigmoidf_(accG[m][n][3]) * mv[3];
      u32x2 pk;
      pk[0] = (uint32_t)f2bf(o0) | ((uint32_t)f2bf(o1) << 16);
      pk[1] = (uint32_t)f2bf(o2) | ((uint32_t)f2bf(o3) << 16);
      const int gsw = (m * 4 + lq) ^ (d & 15);   // 8B granule XOR swizzle
      *(u32x2*)((char*)stage + d * 128 + (gsw << 3)) = pk;
    }
  }
  __syncthreads();

  // --- write phase: quad of 4 lanes emits one full 64B line per round ---
  u16* dstbase = cg ? Bt : At;
  const int q = tid >> 2, il = tid & 3;
#pragma unroll
  for (int r = 0; r < 4; ++r) {
    const int R = q * 4 + r;          // region id [0,256)
    const int d = R >> 1, seg = R & 1;
    const int g0 = seg * 8 + il * 2;  // logical 8B granule
    const u32x2 lo =
        *(const u32x2*)((const char*)stage + d * 128 + ((g0 ^ (d & 15)) << 3));
    const u32x2 hi = *(const u32x2*)((const char*)stage + d * 128 +
                                     (((g0 + 1) ^ (d & 15)) << 3));
    u32x4 outv{lo[0], lo[1], hi[0], hi[1]};
    *(u32x4*)(dstbase + (size_t)d * NROWS + r0 + seg * 32 + il * 8) = outv;
  }

  // --- MFMA pass 2 (round-3 verified layout): gArg = xln @ g_out^T ---
  // acc layout: value(m,reg) is row r_loc = m*16+lq*4+reg, col e = cg*64+w*16+lr
  if (gArg) {
    f32x4 accO[4];
#pragma unroll
    for (int m = 0; m < 4; ++m) accO[m] = f32x4{0.f, 0.f, 0.f, 0.f};
    const int eg = cg * 64 + w * 16 + lr;
#pragma unroll
    for (int ks = 0; ks < 4; ++ks) {
      const int kblk = ks * 4 + lq;
      const ushort8 bO = *(const ushort8*)(Gb + eg * 128 + ks * 32 + lq * 8);
#pragma unroll
      for (int m = 0; m < 4; ++m) {
        const int row = m * 16 + lr;
        const ushort8 af2 = *(const ushort8*)((const char*)xln + row * 256 +
                                              ((kblk ^ (row & 7)) << 4));
        accO[m] = mfma_bf16(af2, bO, accO[m]);
      }
    }
    // stage2[r_loc][e_loc] (2B LDS writes, 8B-granule XOR swizzle)
    const int e_loc = w * 16 + lr;        // [0,64)
    const int gsl = e_loc >> 2;           // logical 8B granule [0,16)
    const int esub = (e_loc & 3) * 2;     // byte within granule
#pragma unroll
    for (int m = 0; m < 4; ++m) {
#pragma unroll
      for (int reg = 0; reg < 4; ++reg) {
        const int rl2 = m * 16 + lq * 4 + reg;
        *(u16*)((char*)stage2 + rl2 * 128 + ((gsl ^ (rl2 & 7)) << 3) + esub) =
            f2bf(accO[m][reg]);
      }
    }
    __syncthreads();
    // read-back: 16B coalesced stores, 8 threads cover one 128B row
#pragma unroll
    for (int p = 0; p < 2; ++p) {
      const int r = p * 32 + (tid >> 3);
      const int il8 = tid & 7;
      const char* base = (const char*)stage2 + r * 128;
      const u32x2 a = *(const u32x2*)(base + (((il8 * 2) ^ (r & 7)) << 3));
      const u32x2 b = *(const u32x2*)(base + (((il8 * 2 + 1) ^ (r & 7)) << 3));
      u32x4 ov{a[0], a[1], b[0], b[1]};
      *(u32x4*)(gArg + (size_t)(r0 + r) * DDIM + cg * 64 + il8 * 8) = ov;
    }
  }
}

// ---------------------------------------------------------------------------
// K2: per-d GEMM  t[i][j][d] = sum_k a[i][k][d] * b[j][k][d]
// Main loop unchanged; C-write now LDS-staged (padded rows) + coalesced 16B.
// ---------------------------------------------------------------------------
__global__ __launch_bounds__(256) void k2_tri(const u16* __restrict__ At,
                                              const u16* __restrict__ Bt,
                                              u16* __restrict__ Ct) {
  __shared__ __align__(16) u16 lds[2 * 16384];  // [buf][A:8192 | B:8192] elems
  const int tid = threadIdx.x;
  const int bid = blockIdx.x;
  const int lb = (bid & 7) * 256 + (bid >> 3);
  const int d = lb >> 4;
  const int tile = lb & 15;
  const int i0 = (tile >> 2) * 128, j0 = (tile & 3) * 128;
  const u16* Ad = At + (size_t)d * NROWS;
  const u16* Bd = Bt + (size_t)d * NROWS;
  const int lane = tid & 63, wid = tid >> 6;
  const int wr = wid >> 1, wc = wid & 1;
  const int lr = lane & 15, lq = lane >> 4;

  f32x4 acc[4][4];
#pragma unroll
  for (int m = 0; m < 4; ++m)
#pragma unroll
    for (int n = 0; n < 4; ++n) acc[m][n] = f32x4{0.f, 0.f, 0.f, 0.f};

  auto stage = [&](int kt, int buf) {
    const int k0 = kt * 64;
#pragma unroll
    for (int q = 0; q < 4; ++q) {
      const int idx = q * 256 + tid;  // 0..1023
      const int r = idx >> 3, bk = idx & 7;
      const int sbk = bk ^ (r & 7);  // pre-swizzled global source
      GLOAD16(Ad + (size_t)(i0 + r) * NSEQ + k0 + sbk * 8,
              &lds[buf * 16384 + idx * 8]);
      GLOAD16(Bd + (size_t)(j0 + r) * NSEQ + k0 + sbk * 8,
              &lds[buf * 16384 + 8192 + idx * 8]);
    }
  };

  stage(0, 0);
  __syncthreads();
  for (int kt = 0; kt < 8; ++kt) {
    const int buf = kt & 1;
    if (kt < 7) stage(kt + 1, buf ^ 1);
    const u16* A_l = &lds[buf * 16384];
    const u16* B_l = &lds[buf * 16384 + 8192];
#pragma unroll
    for (int ks = 0; ks < 2; ++ks) {
      const int kblk = ks * 4 + lq;
      ushort8 af[4], bfr[4];
#pragma unroll
      for (int m = 0; m < 4; ++m) {
        const int row = wr * 64 + m * 16 + lr;
        af[m] = *(const ushort8*)((const char*)A_l + row * 128 +
                                  ((kblk ^ (row & 7)) << 4));
      }
#pragma unroll
      for (int n = 0; n < 4; ++n) {
        const int col = wc * 64 + n * 16 + lr;
        bfr[n] = *(const ushort8*)((const char*)B_l + col * 128 +
                                   ((kblk ^ (col & 7)) << 4));
      }
#pragma unroll
      for (int m = 0; m < 4; ++m)
#pragma unroll
        for (int n = 0; n < 4; ++n)
          acc[m][n] = mfma_bf16(af[m], bfr[n], acc[m][n]);
    }
    __syncthreads();
  }

  // --- C epilogue: stage [128][136] bf16 in LDS, then coalesced 16B out ---
  u16* cst = lds;  // free after final barrier; 128*136 = 17408 elems < 32768
#pragma unroll
  for (int m = 0; m < 4; ++m) {
#pragma unroll
    for (int n = 0; n < 4; ++n) {
      const int jl = wc * 64 + n * 16 + lr;
#pragma unroll
      for (int reg = 0; reg < 4; ++reg) {
        const int il = wr * 64 + m * 16 + lq * 4 + reg;
        cst[il * 136 + jl] = f2bf(acc[m][n][reg]);
      }
    }
  }
  __syncthreads();
  u16* Cd = Ct + (size_t)d * NROWS;
  {
    const int r = tid >> 1, half = tid & 1;
#pragma unroll
    for (int k = 0; k < 8; ++k) {
      const u32x4 v = *(const u32x4*)(cst + r * 136 + half * 64 + k * 8);
      *(u32x4*)(Cd + (size_t)(i0 + r) * NSEQ + j0 + half * 64 + k * 8) = v;
    }
  }
}

// ---------------------------------------------------------------------------
// K3 (round-3 version, verbatim): out = (rs*(T@P'^T)+affine)*sigmoid(gArg)
// ---------------------------------------------------------------------------
__global__ __launch_bounds__(256, 4) void k3_out(
    const u16* __restrict__ Ct, const u16* __restrict__ gArg,
    const u16* __restrict__ Pb, const float* __restrict__ S12,
    float* __restrict__ out) {
  __shared__ __align__(16) u16 ldsT[128 * 128];  // [r][d], 16B XOR swizzle
  __shared__ float ps[4 * 128], pss[4 * 128];
  __shared__ float prm[128 * 2];
  __shared__ float s12l[128 * 2];
  const int tid = threadIdx.x, lane = tid & 63, w = tid >> 6;
  const int c0 = blockIdx.x * 128;

  // --- phase A: all 4 waves stream Ct columns; wave w = d-quarter w ---
  {
    const int row2 = lane * 2;  // rows row2, row2+1
    const u16* cp = Ct + c0 + row2;
    float s0 = 0.f, ss0 = 0.f, s1 = 0.f, ss1 = 0.f;
#pragma unroll
    for (int db = 0; db < 4; ++db) {
      uint32_t pe[4], po[4];
#pragma unroll
      for (int j = 0; j < 8; ++j) {
        const int d = w * 32 + db * 8 + j;
        const uint32_t v = *(const uint32_t*)(cp + (size_t)d * NROWS);
        const u16 ue = (u16)v, uo = (u16)(v >> 16);
        const float fe = bf2f(ue), fo = bf2f(uo);
        s0 += fe; ss0 += fe * fe;
        s1 += fo; ss1 += fo * fo;
        if (j & 1) {
          pe[j >> 1] |= ((uint32_t)ue) << 16;
          po[j >> 1] |= ((uint32_t)uo) << 16;
        } else {
          pe[j >> 1] = ue;
          po[j >> 1] = uo;
        }
      }
      const int gr = w * 4 + db;  // granule 0..15 (8 d's each)
      *(u32x4*)((char*)ldsT + row2 * 256 + ((gr ^ (row2 & 7)) << 4)) =
          u32x4{pe[0], pe[1], pe[2], pe[3]};
      *(u32x4*)((char*)ldsT + (row2 + 1) * 256 + ((gr ^ ((row2 + 1) & 7)) << 4)) =
          u32x4{po[0], po[1], po[2], po[3]};
    }
    ps[w * 128 + row2] = s0;
    pss[w * 128 + row2] = ss0;
    ps[w * 128 + row2 + 1] = s1;
    pss[w * 128 + row2 + 1] = ss1;
  }
  if (tid < 128) ((u32x2*)s12l)[tid] = ((const u32x2*)S12)[tid];
  __syncthreads();
  if (tid < 128) {
    const float s = ps[tid] + ps[128 + tid] + ps[256 + tid] + ps[384 + tid];
    const float ss = pss[tid] + pss[128 + tid] + pss[256 + tid] + pss[384 + tid];
    const float mu = s * (1.f / 128.f);
    const float rs = rsqrtf(ss * (1.f / 128.f) - mu * mu + 1e-5f);
    prm[2 * tid] = rs;
    prm[2 * tid + 1] = -rs * mu;
  }

  // --- MFMA: wave w owns rows [w*32, w*32+32), all 128 e cols ---
  const int lr = lane & 15, lq = lane >> 4;
  const int rowbase = w * 32;
  f32x4 aP[2][8];
#pragma unroll
  for (int m = 0; m < 2; ++m)
#pragma unroll
    for (int n = 0; n < 8; ++n) aP[m][n] = f32x4{0.f, 0.f, 0.f, 0.f};
#pragma unroll
  for (int ks = 0; ks < 4; ++ks) {
    const int kblk = ks * 4 + lq;
    ushort8 at2[2];
#pragma unroll
    for (int m = 0; m < 2; ++m) {
      const int row = rowbase + m * 16 + lr;
      at2[m] = *(const ushort8*)((const char*)ldsT + row * 256 +
                                 ((kblk ^ (row & 7)) << 4));
    }
    ushort8 bp[8];
#pragma unroll
    for (int n = 0; n < 8; ++n) {
      const int e = n * 16 + lr;
      bp[n] = *(const ushort8*)(Pb + e * 128 + ks * 32 + lq * 8);
    }
#pragma unroll
    for (int m = 0; m < 2; ++m)
#pragma unroll
      for (int n = 0; n < 8; ++n) aP[m][n] = mfma_bf16(at2[m], bp[n], aP[m][n]);
  }
  __syncthreads();  // prm/s12l ready for epilogue

  // --- epilogue ---
#pragma unroll
  for (int m = 0; m < 2; ++m) {
    const int crow = rowbase + m * 16 + lq * 4;
#pragma unroll
    for (int n = 0; n < 8; ++n) {
      const int e = n * 16 + lr;
      const float s1 = s12l[2 * e], s2v = s12l[2 * e + 1];
#pragma unroll
      for (int reg = 0; reg < 4; ++reg) {
        const float rs = prm[2 * (crow + reg)];
        const float t1 = prm[2 * (crow + reg) + 1];
        const float op = rs * aP[m][n][reg] + t1 * s1 + s2v;
        const size_t r = (size_t)(c0 + crow + reg);
        const float gt = sigmoidf_(bf2f(gArg[r * DDIM + e]));
        out[r * DDIM + e] = op * gt;
      }
    }
  }
}

// ---------------------------------------------------------------------------
// K3 fallback (Round-2 version, verbatim): used when ws too small for gArg.
// ---------------------------------------------------------------------------
__global__ __launch_bounds__(256) void k3_fb(
    const float* __restrict__ x, const u16* __restrict__ Ct,
    const float* __restrict__ niw, const float* __restrict__ nib,
    const u16* __restrict__ Pb, const u16* __restrict__ Gb,
    const float* __restrict__ S12, float* __restrict__ out) {
  __shared__ __align__(16) u16 ldsX[128 * 128];
  __shared__ __align__(16) u16 ldsT[128 * 128];
  __shared__ __align__(16) float prm[128 * 2];
  __shared__ __align__(16) float s12l[128 * 2];
  const int tid = threadIdx.x, lane = tid & 63, w = tid >> 6;
  const int c0 = blockIdx.x * 128;

  if (w < 2) {
    ((u32x2*)s12l)[tid] = ((const u32x2*)S12)[tid];
    const int cloc = w * 64 + lane;
    const u16* cp = Ct + c0 + cloc;
    float s = 0.f, ss = 0.f;
    for (int db = 0; db < 16; ++db) {
      uint32_t pk[4];
#pragma unroll
      for (int j = 0; j < 8; ++j) {
        const u16 u = cp[(size_t)(db * 8 + j) * NROWS];
        const float v = bf2f(u);
        s += v;
        ss += v * v;
        if (j & 1)
          pk[j >> 1] |= ((uint32_t)u) << 16;
        else
          pk[j >> 1] = (uint32_t)u;
      }
      const int byteoff = cloc * 256 + ((db ^ (cloc & 7)) << 4);
      *(u32x4*)((char*)ldsT + byteoff) = u32x4{pk[0], pk[1], pk[2], pk[3]};
    }
    const float mu = s * (1.f / 128.f);
    const float rs = rsqrtf(ss * (1.f / 128.f) - mu * mu + 1e-5f);
    prm[2 * cloc] = rs;
    prm[2 * cloc + 1] = -rs * mu;
  } else {
    const int g = lane >> 4, c = lane & 15;
    for (int it = 0; it < 16; ++it) {
      const int rl = (w - 2) * 64 + it * 4 + g;
      const float* xr = x + (size_t)(c0 + rl) * DDIM + c * 8;
      f32x4 v0 = *(const f32x4*)xr;
      f32x4 v1 = *(const f32x4*)(xr + 4);
      float s = v0[0] + v0[1] + v0[2] + v0[3] + v1[0] + v1[1] + v1[2] + v1[3];
      float ss = v0[0] * v0[0] + v0[1] * v0[1] + v0[2] * v0[2] + v0[3] * v0[3] +
                 v1[0] * v1[0] + v1[1] * v1[1] + v1[2] * v1[2] + v1[3] * v1[3];
#pragma unroll
      for (int m = 1; m < 16; m <<= 1) {
        s += __shfl_xor(s, m);
        ss += __shfl_xor(ss, m);
      }
      const float mu = s * (1.0f / 128.0f);
      const float rs = rsqrtf(ss * (1.0f / 128.0f) - mu * mu + 1e-5f);
      f32x4 w0 = *(const f32x4*)(niw + c * 8);
      f32x4 w1 = *(const f32x4*)(niw + c * 8 + 4);
      f32x4 b0 = *(const f32x4*)(nib + c * 8);
      f32x4 b1 = *(const f32x4*)(nib + c * 8 + 4);
      ushort8 o;
#pragma unroll
      for (int j = 0; j < 4; ++j) o[j] = f2bf((v0[j] - mu) * rs * w0[j] + b0[j]);
#pragma unroll
      for (int j = 0; j < 4; ++j)
        o[4 + j] = f2bf((v1[j] - mu) * rs * w1[j] + b1[j]);
      const int byteoff = rl * 256 + ((c ^ (rl & 7)) << 4);
      *(ushort8*)((char*)ldsX + byteoff) = o;
    }
  }
  __syncthreads();

  const int lr = lane & 15, lq = lane >> 4;
  const int rowbase = w * 32;
#pragma unroll
  for (int h = 0; h < 2; ++h) {
    f32x4 aG[2][4], aP[2][4];
#pragma unroll
    for (int m = 0; m < 2; ++m)
#pragma unroll
      for (int n = 0; n < 4; ++n) {
        aG[m][n] = f32x4{0.f, 0.f, 0.f, 0.f};
        aP[m][n] = f32x4{0.f, 0.f, 0.f, 0.f};
      }
#pragma unroll
    for (int ks = 0; ks < 4; ++ks) {
      const int kblk = ks * 4 + lq;
      ushort8 ax[2], at2[2];
#pragma unroll
      for (int m = 0; m < 2; ++m) {
        const int row = rowbase + m * 16 + lr;
        const int off = row * 256 + ((kblk ^ (row & 7)) << 4);
        ax[m] = *(const ushort8*)((const char*)ldsX + off);
        at2[m] = *(const ushort8*)((const char*)ldsT + off);
      }
      ushort8 bg[4], bp[4];
#pragma unroll
      for (int n = 0; n < 4; ++n) {
        const int e = h * 64 + n * 16 + lr;
        const int dd = ks * 32 + lq * 8;
        bg[n] = *(const ushort8*)(Gb + e * 128 + dd);
        bp[n] = *(const ushort8*)(Pb + e * 128 + dd);
      }
#pragma unroll
      for (int m = 0; m < 2; ++m)
#pragma unroll
        for (int n = 0; n < 4; ++n) {
          aG[m][n] = mfma_bf16(ax[m], bg[n], aG[m][n]);
          aP[m][n] = mfma_bf16(at2[m], bp[n], aP[m][n]);
        }
    }
#pragma unroll
    for (int m = 0; m < 2; ++m) {
      const int crow = rowbase + m * 16 + lq * 4;
#pragma unroll
      for (int n = 0; n < 4; ++n) {
        const int e = h * 64 + n * 16 + lr;
        const float s1 = s12l[2 * e], s2v = s12l[2 * e + 1];
#pragma unroll
        for (int reg = 0; reg < 4; ++reg) {
          const float rs = prm[2 * (crow + reg)];
          const float t1 = prm[2 * (crow + reg) + 1];
          const float op = rs * aP[m][n][reg] + t1 * s1 + s2v;
          const float gt = sigmoidf_(aG[m][n][reg]);
          out[(size_t)(c0 + crow + reg) * DDIM + e] = op * gt;
        }
      }
    }
  }
}

// ---------------------------------------------------------------------------
extern "C" void kernel_launch(void* const* d_in, const int* in_sizes, int n_in,
                              void* d_out, int out_size, void* d_ws,
                              size_t ws_size, hipStream_t stream) {
  const float* x = (const float*)d_in[0];
  const float* mask = (const float*)d_in[1];
  const float* niw = (const float*)d_in[2];
  const float* nib = (const float*)d_in[3];
  const float* p_in_w = (const float*)d_in[4];
  const float* g_in_w = (const float*)d_in[5];
  const float* now = (const float*)d_in[6];
  const float* nob = (const float*)d_in[7];
  const float* p_out_w = (const float*)d_in[8];
  const float* g_out_w = (const float*)d_in[9];
  float* out = (float*)d_out;
  char* ws = (char*)d_ws;

  const bool big = ws_size >= (size_t)268633088;  // fits gArg layout

  u16 *At, *Bt, *Ct, *gA, *Wb, *Pb, *Gb;
  float* S12;
  if (big) {
    At = (u16*)(ws);                     // 64 MiB
    Bt = (u16*)(ws + 67108864);          // 64 MiB
    Ct = (u16*)(ws + 134217728);         // 64 MiB
    gA = (u16*)(ws + 201326592);         // 64 MiB
    Wb = (u16*)(ws + 268435456);         // 128 KiB
    Pb = (u16*)(ws + 268566528);         // 32 KiB
    Gb = (u16*)(ws + 268599296);         // 32 KiB
    S12 = (float*)(ws + 268632064);      // 1 KiB
  } else {
    At = (u16*)(ws);
    Bt = (u16*)(ws + 67108864);
    Ct = (u16*)(ws + 134217728);
    gA = nullptr;
    Wb = (u16*)(ws + 201326592);
    Pb = (u16*)(ws + 201457664);
    Gb = (u16*)(ws + 201490432);
    S12 = (float*)(ws + 201523200);
  }

  hipLaunchKernelGGL(k0_prep, dim3(1), dim3(256), 0, stream, p_in_w, g_in_w,
                     p_out_w, g_out_w, now, nob, Wb, Pb, Gb, S12);
  hipLaunchKernelGGL(k1_ln_proj, dim3(2 * NROWS / 64), dim3(256), 0, stream, x,
                     mask, niw, nib, Wb, Gb, At, Bt, gA);
  hipLaunchKernelGGL(k2_tri, dim3(128 * 16), dim3(256), 0, stream, At, Bt, Ct);
  if (big) {
    hipLaunchKernelGGL(k3_out, dim3(NROWS / 128), dim3(256), 0, stream, Ct, gA,
                       Pb, S12, out);
  } else {
    hipLaunchKernelGGL(k3_fb, dim3(NROWS / 128), dim3(256), 0, stream, x, Ct,
                       niw, nib, Pb, Gb, S12, out);
  }
}

// Round 6
// 417.055 us; speedup vs baseline: 1.0048x; 1.0048x over previous
//
#include <hip/hip_runtime.h>
#include <stdint.h>

#define NSEQ 512
#define DDIM 128
#define NROWS (NSEQ * NSEQ)   // 262144

typedef __bf16 bf16x8 __attribute__((ext_vector_type(8)));
typedef __bf16 bf16x2v __attribute__((ext_vector_type(2)));
typedef unsigned short u16;
typedef u16 ushort8 __attribute__((ext_vector_type(8)));
typedef float f32x4 __attribute__((ext_vector_type(4)));
typedef uint32_t u32x4 __attribute__((ext_vector_type(4)));
typedef uint32_t u32x2 __attribute__((ext_vector_type(2)));

// native RNE converts (compiler emits v_cvt_f32->bf16 / v_cvt_pk_bf16_f32)
__device__ __forceinline__ u16 cvt1(float f) {
  return __builtin_bit_cast(u16, (__bf16)f);
}
__device__ __forceinline__ uint32_t pk2(float a, float b) {
  bf16x2v v = {(__bf16)a, (__bf16)b};
  return __builtin_bit_cast(uint32_t, v);
}
__device__ __forceinline__ float bf2f(u16 u) {
  uint32_t x = ((uint32_t)u) << 16;
  return __builtin_bit_cast(float, x);
}
__device__ __forceinline__ f32x4 mfma_bf16(ushort8 a, ushort8 b, f32x4 c) {
  return __builtin_amdgcn_mfma_f32_16x16x32_bf16(
      __builtin_bit_cast(bf16x8, a), __builtin_bit_cast(bf16x8, b), c, 0, 0, 0);
}
__device__ __forceinline__ float sigmoidf_(float x) {
  return 1.0f / (1.0f + __expf(-x));
}

#define GLOAD16(gp, lp)                                                        \
  __builtin_amdgcn_global_load_lds(                                            \
      (const __attribute__((address_space(1))) void*)(gp),                     \
      (__attribute__((address_space(3))) void*)(lp), 16, 0, 0)

// ---------------------------------------------------------------------------
// K0: weight prep (unchanged semantics).
// ---------------------------------------------------------------------------
__global__ void k0_prep(const float* __restrict__ p_in_w,
                        const float* __restrict__ g_in_w,
                        const float* __restrict__ p_out_w,
                        const float* __restrict__ g_out_w,
                        const float* __restrict__ now,
                        const float* __restrict__ nob,
                        u16* __restrict__ Wb, u16* __restrict__ Pb,
                        u16* __restrict__ Gb, float* __restrict__ S12) {
  const int t = threadIdx.x;  // 256 threads, 1 block
  for (int idx = t; idx < 512 * 128; idx += 256) {
    const int e = idx >> 7, d = idx & 127;
    const float v = (e < 256) ? p_in_w[e * 128 + d] : g_in_w[(e - 256) * 128 + d];
    Wb[idx] = cvt1(v);
  }
  for (int idx = t; idx < 128 * 128; idx += 256) {
    const int d = idx & 127;
    Pb[idx] = cvt1(p_out_w[idx] * now[d]);
    Gb[idx] = cvt1(g_out_w[idx]);
  }
  if (t < 128) {
    float s1 = 0.f, s2 = 0.f;
    for (int d = 0; d < 128; ++d) {
      s1 += p_out_w[t * 128 + d] * now[d];
      s2 += p_out_w[t * 128 + d] * nob[d];
    }
    S12[2 * t] = s1;
    S12[2 * t + 1] = s2;
  }
}

// ---------------------------------------------------------------------------
// K1 (4-way column split): grid 16384 = (rb: 4096 row-blocks of 64) x (cg: 4).
//   cg 0,1 -> P cols [cg*64, cg*64+64) -> At cols; gate-in cols +256
//   cg 2,3 -> P cols [cg*64, ...)      -> Bt cols (E-128)
// Per wave: 64 rows x (16 P + 16 G cols): accP[4]+accG[4] = 32 f32 acc ->
// ~6 waves/SIMD occupancy (vs 4 at the old 64-float acc).
// Pass 2 (cg<2 only): gArg[r][e] = xln @ g_out^T, verbatim r5 code; stage2
// aliases stage (barrier-separated) so LDS = 24KB.
// Decode keeps all 4 cg of one rb on the same XCD (bid&7 equal).
// ---------------------------------------------------------------------------
__global__ __launch_bounds__(256, 6) void k1_ln_proj(
    const float* __restrict__ x, const float* __restrict__ mask,
    const float* __restrict__ niw, const float* __restrict__ nib,
    const u16* __restrict__ Wb, const u16* __restrict__ Gb,
    u16* __restrict__ At, u16* __restrict__ Bt, u16* __restrict__ gArg) {
  __shared__ __align__(16) u16 xln[64 * 128];   // 16KB, 16B-granule XOR swizzle
  __shared__ __align__(16) u16 stage[64 * 64];  // 8KB [d][r]; reused as stage2[r][e]
  const int tid = threadIdx.x;
  const int lane = tid & 63;
  const int w = tid >> 6;
  const int bid = blockIdx.x;
  const int rb = (bid >> 5) * 8 + (bid & 7);
  const int cg = (bid >> 3) & 3;
  const int r0 = rb * 64;
  const int g = lane >> 4, c = lane & 15;

  // --- LN phase: wave w rows [w*16, w*16+16), 4 rows/iter (verbatim) ---
  f32x4 v0[4], v1[4];
#pragma unroll
  for (int it = 0; it < 4; ++it) {
    const int rl = w * 16 + it * 4 + g;
    const float* xr = x + (size_t)(r0 + rl) * DDIM + c * 8;
    v0[it] = *(const f32x4*)xr;
    v1[it] = *(const f32x4*)(xr + 4);
  }
  const f32x4 w0 = *(const f32x4*)(niw + c * 8);
  const f32x4 w1 = *(const f32x4*)(niw + c * 8 + 4);
  const f32x4 b0 = *(const f32x4*)(nib + c * 8);
  const f32x4 b1 = *(const f32x4*)(nib + c * 8 + 4);
#pragma unroll
  for (int it = 0; it < 4; ++it) {
    const int rl = w * 16 + it * 4 + g;
    float s = v0[it][0] + v0[it][1] + v0[it][2] + v0[it][3] +
              v1[it][0] + v1[it][1] + v1[it][2] + v1[it][3];
    float ss = v0[it][0] * v0[it][0] + v0[it][1] * v0[it][1] +
               v0[it][2] * v0[it][2] + v0[it][3] * v0[it][3] +
               v1[it][0] * v1[it][0] + v1[it][1] * v1[it][1] +
               v1[it][2] * v1[it][2] + v1[it][3] * v1[it][3];
#pragma unroll
    for (int m = 1; m < 16; m <<= 1) {
      s += __shfl_xor(s, m);
      ss += __shfl_xor(ss, m);
    }
    const float mu = s * (1.0f / 128.0f);
    const float rs = rsqrtf(ss * (1.0f / 128.0f) - mu * mu + 1e-5f);
    float f0 = (v0[it][0] - mu) * rs * w0[0] + b0[0];
    float f1 = (v0[it][1] - mu) * rs * w0[1] + b0[1];
    float f2 = (v0[it][2] - mu) * rs * w0[2] + b0[2];
    float f3 = (v0[it][3] - mu) * rs * w0[3] + b0[3];
    float f4 = (v1[it][0] - mu) * rs * w1[0] + b1[0];
    float f5 = (v1[it][1] - mu) * rs * w1[1] + b1[1];
    float f6 = (v1[it][2] - mu) * rs * w1[2] + b1[2];
    float f7 = (v1[it][3] - mu) * rs * w1[3] + b1[3];
    u32x4 ov{pk2(f0, f1), pk2(f2, f3), pk2(f4, f5), pk2(f6, f7)};
    const int byteoff = rl * 256 + ((c ^ (rl & 7)) << 4);
    *(u32x4*)((char*)xln + byteoff) = ov;
  }
  __syncthreads();

  // --- MFMA pass 1: wave w -> P col block eP..eP+16, G cols eP+256.. ---
  const int lr = lane & 15, lq = lane >> 4;
  const int eP = cg * 64 + w * 16;   // global P col base for this wave [0,256)
  f32x4 accP[4], accG[4];
#pragma unroll
  for (int m = 0; m < 4; ++m) {
    accP[m] = f32x4{0.f, 0.f, 0.f, 0.f};
    accG[m] = f32x4{0.f, 0.f, 0.f, 0.f};
  }

#pragma unroll
  for (int ks = 0; ks < 4; ++ks) {
    const int kblk = ks * 4 + lq;
    ushort8 af[4];
#pragma unroll
    for (int m = 0; m < 4; ++m) {
      const int row = m * 16 + lr;
      af[m] = *(const ushort8*)((const char*)xln + row * 256 +
                                ((kblk ^ (row & 7)) << 4));
    }
    const int e = eP + lr;
    const int dd = ks * 32 + lq * 8;
    const ushort8 bP = *(const ushort8*)(Wb + e * 128 + dd);
    const ushort8 bG = *(const ushort8*)(Wb + (256 + e) * 128 + dd);
#pragma unroll
    for (int m = 0; m < 4; ++m) {
      accP[m] = mfma_bf16(af[m], bP, accP[m]);
      accG[m] = mfma_bf16(af[m], bG, accG[m]);
    }
  }

  // --- epilogue: gate + mask -> swizzled LDS stage [d][r] (d in [0,64)) ---
  const int dloc = w * 16 + lr;  // col within this block's 64-col output
#pragma unroll
  for (int m = 0; m < 4; ++m) {
    const int rloc = m * 16 + lq * 4;
    const f32x4 mv = *(const f32x4*)(mask + r0 + rloc);
    const float o0 = accP[m][0] * sigmoidf_(accG[m][0]) * mv[0];
    const float o1 = accP[m][1] * sigmoidf_(accG[m][1]) * mv[1];
    const float o2 = accP[m][2] * sigmoidf_(accG[m][2]) * mv[2];
    const float o3 = accP[m][3] * sigmoidf_(accG[m][3]) * mv[3];
    u32x2 pk;
    pk[0] = pk2(o0, o1);
    pk[1] = pk2(o2, o3);
    const int gsw = (m * 4 + lq) ^ (dloc & 15);  // 8B granule XOR swizzle
    *(u32x2*)((char*)stage + dloc * 128 + (gsw << 3)) = pk;
  }
  __syncthreads();

  // --- write phase: full 64B-line coalesced stores (2 per thread) ---
  {
    u16* dstbase = (cg >= 2) ? Bt : At;
    const int colbase = (cg & 1) * 64;
    const int R = tid >> 1;            // region [0,128)
    const int dl = R >> 1, seg = R & 1;
#pragma unroll
    for (int rr = 0; rr < 2; ++rr) {
      const int il = (tid & 1) * 2 + rr;  // [0,4)
      const int g0 = seg * 8 + il * 2;    // logical 8B granule
      const u32x2 lo =
          *(const u32x2*)((const char*)stage + dl * 128 + ((g0 ^ (dl & 15)) << 3));
      const u32x2 hi = *(const u32x2*)((const char*)stage + dl * 128 +
                                       (((g0 + 1) ^ (dl & 15)) << 3));
      u32x4 outv{lo[0], lo[1], hi[0], hi[1]};
      *(u32x4*)(dstbase + (size_t)(colbase + dl) * NROWS + r0 + seg * 32 +
                il * 8) = outv;
    }
  }

  // --- MFMA pass 2 (cg 0,1 only; r5-verified layout): gArg = xln @ g_out^T ---
  if (cg < 2) {
    f32x4 accO[4];
#pragma unroll
    for (int m = 0; m < 4; ++m) accO[m] = f32x4{0.f, 0.f, 0.f, 0.f};
    const int eg = cg * 64 + w * 16 + lr;
#pragma unroll
    for (int ks = 0; ks < 4; ++ks) {
      const int kblk = ks * 4 + lq;
      const ushort8 bO = *(const ushort8*)(Gb + eg * 128 + ks * 32 + lq * 8);
#pragma unroll
      for (int m = 0; m < 4; ++m) {
        const int row = m * 16 + lr;
        const ushort8 af2 = *(const ushort8*)((const char*)xln + row * 256 +
                                              ((kblk ^ (row & 7)) << 4));
        accO[m] = mfma_bf16(af2, bO, accO[m]);
      }
    }
    __syncthreads();  // all threads done reading `stage` -> safe to alias
    // stage2[r_loc][e_loc] (2B LDS writes, 8B-granule XOR swizzle)
    u16* stage2 = stage;
    const int e_loc = w * 16 + lr;        // [0,64)
    const int gsl = e_loc >> 2;           // logical 8B granule [0,16)
    const int esub = (e_loc & 3) * 2;     // byte within granule
#pragma unroll
    for (int m = 0; m < 4; ++m) {
#pragma unroll
      for (int reg = 0; reg < 4; ++reg) {
        const int rl2 = m * 16 + lq * 4 + reg;
        *(u16*)((char*)stage2 + rl2 * 128 + ((gsl ^ (rl2 & 7)) << 3) + esub) =
            cvt1(accO[m][reg]);
      }
    }
    __syncthreads();
    // read-back: 16B coalesced stores, 8 threads cover one 128B row
#pragma unroll
    for (int p = 0; p < 2; ++p) {
      const int r = p * 32 + (tid >> 3);
      const int il8 = tid & 7;
      const char* base = (const char*)stage2 + r * 128;
      const u32x2 a = *(const u32x2*)(base + (((il8 * 2) ^ (r & 7)) << 3));
      const u32x2 b = *(const u32x2*)(base + (((il8 * 2 + 1) ^ (r & 7)) << 3));
      u32x4 ov{a[0], a[1], b[0], b[1]};
      *(u32x4*)(gArg + (size_t)(r0 + r) * DDIM + cg * 64 + il8 * 8) = ov;
    }
  }
}

// ---------------------------------------------------------------------------
// K2: per-d GEMM  t[i][j][d] = sum_k a[i][k][d] * b[j][k][d]
// (round-3 version: direct C stores; native casts)
// ---------------------------------------------------------------------------
__global__ __launch_bounds__(256) void k2_tri(const u16* __restrict__ At,
                                              const u16* __restrict__ Bt,
                                              u16* __restrict__ Ct) {
  __shared__ __align__(16) u16 lds[2 * 16384];  // [buf][A:8192 | B:8192] elems
  const int tid = threadIdx.x;
  const int bid = blockIdx.x;
  const int lb = (bid & 7) * 256 + (bid >> 3);
  const int d = lb >> 4;
  const int tile = lb & 15;
  const int i0 = (tile >> 2) * 128, j0 = (tile & 3) * 128;
  const u16* Ad = At + (size_t)d * NROWS;
  const u16* Bd = Bt + (size_t)d * NROWS;
  const int lane = tid & 63, wid = tid >> 6;
  const int wr = wid >> 1, wc = wid & 1;
  const int lr = lane & 15, lq = lane >> 4;

  f32x4 acc[4][4];
#pragma unroll
  for (int m = 0; m < 4; ++m)
#pragma unroll
    for (int n = 0; n < 4; ++n) acc[m][n] = f32x4{0.f, 0.f, 0.f, 0.f};

  auto stage = [&](int kt, int buf) {
    const int k0 = kt * 64;
#pragma unroll
    for (int q = 0; q < 4; ++q) {
      const int idx = q * 256 + tid;  // 0..1023
      const int r = idx >> 3, bk = idx & 7;
      const int sbk = bk ^ (r & 7);  // pre-swizzled global source
      GLOAD16(Ad + (size_t)(i0 + r) * NSEQ + k0 + sbk * 8,
              &lds[buf * 16384 + idx * 8]);
      GLOAD16(Bd + (size_t)(j0 + r) * NSEQ + k0 + sbk * 8,
              &lds[buf * 16384 + 8192 + idx * 8]);
    }
  };

  stage(0, 0);
  __syncthreads();
  for (int kt = 0; kt < 8; ++kt) {
    const int buf = kt & 1;
    if (kt < 7) stage(kt + 1, buf ^ 1);
    const u16* A_l = &lds[buf * 16384];
    const u16* B_l = &lds[buf * 16384 + 8192];
#pragma unroll
    for (int ks = 0; ks < 2; ++ks) {
      const int kblk = ks * 4 + lq;
      ushort8 af[4], bfr[4];
#pragma unroll
      for (int m = 0; m < 4; ++m) {
        const int row = wr * 64 + m * 16 + lr;
        af[m] = *(const ushort8*)((const char*)A_l + row * 128 +
                                  ((kblk ^ (row & 7)) << 4));
      }
#pragma unroll
      for (int n = 0; n < 4; ++n) {
        const int col = wc * 64 + n * 16 + lr;
        bfr[n] = *(const ushort8*)((const char*)B_l + col * 128 +
                                   ((kblk ^ (col & 7)) << 4));
      }
#pragma unroll
      for (int m = 0; m < 4; ++m)
#pragma unroll
        for (int n = 0; n < 4; ++n)
          acc[m][n] = mfma_bf16(af[m], bfr[n], acc[m][n]);
    }
    __syncthreads();
  }

  u16* Cd = Ct + (size_t)d * NROWS;
#pragma unroll
  for (int m = 0; m < 4; ++m) {
    const int i = i0 + wr * 64 + m * 16 + lq * 4;
#pragma unroll
    for (int n = 0; n < 4; ++n) {
      const int j = j0 + wc * 64 + n * 16 + lr;
#pragma unroll
      for (int reg = 0; reg < 4; ++reg)
        Cd[(size_t)(i + reg) * NSEQ + j] = cvt1(acc[m][n][reg]);
    }
  }
}

// ---------------------------------------------------------------------------
// K3 (r5 verbatim): out = (rs*(T@P'^T)+affine)*sigmoid(gArg)
// ---------------------------------------------------------------------------
__global__ __launch_bounds__(256, 4) void k3_out(
    const u16* __restrict__ Ct, const u16* __restrict__ gArg,
    const u16* __restrict__ Pb, const float* __restrict__ S12,
    float* __restrict__ out) {
  __shared__ __align__(16) u16 ldsT[128 * 128];  // [r][d], 16B XOR swizzle
  __shared__ float ps[4 * 128], pss[4 * 128];
  __shared__ float prm[128 * 2];
  __shared__ float s12l[128 * 2];
  const int tid = threadIdx.x, lane = tid & 63, w = tid >> 6;
  const int c0 = blockIdx.x * 128;

  // --- phase A: all 4 waves stream Ct columns; wave w = d-quarter w ---
  {
    const int row2 = lane * 2;  // rows row2, row2+1
    const u16* cp = Ct + c0 + row2;
    float s0 = 0.f, ss0 = 0.f, s1 = 0.f, ss1 = 0.f;
#pragma unroll
    for (int db = 0; db < 4; ++db) {
      uint32_t pe[4], po[4];
#pragma unroll
      for (int j = 0; j < 8; ++j) {
        const int d = w * 32 + db * 8 + j;
        const uint32_t v = *(const uint32_t*)(cp + (size_t)d * NROWS);
        const u16 ue = (u16)v, uo = (u16)(v >> 16);
        const float fe = bf2f(ue), fo = bf2f(uo);
        s0 += fe; ss0 += fe * fe;
        s1 += fo; ss1 += fo * fo;
        if (j & 1) {
          pe[j >> 1] |= ((uint32_t)ue) << 16;
          po[j >> 1] |= ((uint32_t)uo) << 16;
        } else {
          pe[j >> 1] = ue;
          po[j >> 1] = uo;
        }
      }
      const int gr = w * 4 + db;  // granule 0..15 (8 d's each)
      *(u32x4*)((char*)ldsT + row2 * 256 + ((gr ^ (row2 & 7)) << 4)) =
          u32x4{pe[0], pe[1], pe[2], pe[3]};
      *(u32x4*)((char*)ldsT + (row2 + 1) * 256 + ((gr ^ ((row2 + 1) & 7)) << 4)) =
          u32x4{po[0], po[1], po[2], po[3]};
    }
    ps[w * 128 + row2] = s0;
    pss[w * 128 + row2] = ss0;
    ps[w * 128 + row2 + 1] = s1;
    pss[w * 128 + row2 + 1] = ss1;
  }
  if (tid < 128) ((u32x2*)s12l)[tid] = ((const u32x2*)S12)[tid];
  __syncthreads();
  if (tid < 128) {
    const float s = ps[tid] + ps[128 + tid] + ps[256 + tid] + ps[384 + tid];
    const float ss = pss[tid] + pss[128 + tid] + pss[256 + tid] + pss[384 + tid];
    const float mu = s * (1.f / 128.f);
    const float rs = rsqrtf(ss * (1.f / 128.f) - mu * mu + 1e-5f);
    prm[2 * tid] = rs;
    prm[2 * tid + 1] = -rs * mu;
  }

  // --- MFMA: wave w owns rows [w*32, w*32+32), all 128 e cols ---
  const int lr = lane & 15, lq = lane >> 4;
  const int rowbase = w * 32;
  f32x4 aP[2][8];
#pragma unroll
  for (int m = 0; m < 2; ++m)
#pragma unroll
    for (int n = 0; n < 8; ++n) aP[m][n] = f32x4{0.f, 0.f, 0.f, 0.f};
#pragma unroll
  for (int ks = 0; ks < 4; ++ks) {
    const int kblk = ks * 4 + lq;
    ushort8 at2[2];
#pragma unroll
    for (int m = 0; m < 2; ++m) {
      const int row = rowbase + m * 16 + lr;
      at2[m] = *(const ushort8*)((const char*)ldsT + row * 256 +
                                 ((kblk ^ (row & 7)) << 4));
    }
    ushort8 bp[8];
#pragma unroll
    for (int n = 0; n < 8; ++n) {
      const int e = n * 16 + lr;
      bp[n] = *(const ushort8*)(Pb + e * 128 + ks * 32 + lq * 8);
    }
#pragma unroll
    for (int m = 0; m < 2; ++m)
#pragma unroll
      for (int n = 0; n < 8; ++n) aP[m][n] = mfma_bf16(at2[m], bp[n], aP[m][n]);
  }
  __syncthreads();  // prm/s12l ready for epilogue

  // --- epilogue ---
#pragma unroll
  for (int m = 0; m < 2; ++m) {
    const int crow = rowbase + m * 16 + lq * 4;
#pragma unroll
    for (int n = 0; n < 8; ++n) {
      const int e = n * 16 + lr;
      const float s1 = s12l[2 * e], s2v = s12l[2 * e + 1];
#pragma unroll
      for (int reg = 0; reg < 4; ++reg) {
        const float rs = prm[2 * (crow + reg)];
        const float t1 = prm[2 * (crow + reg) + 1];
        const float op = rs * aP[m][n][reg] + t1 * s1 + s2v;
        const size_t r = (size_t)(c0 + crow + reg);
        const float gt = sigmoidf_(bf2f(gArg[r * DDIM + e]));
        out[r * DDIM + e] = op * gt;
      }
    }
  }
}

// ---------------------------------------------------------------------------
extern "C" void kernel_launch(void* const* d_in, const int* in_sizes, int n_in,
                              void* d_out, int out_size, void* d_ws,
                              size_t ws_size, hipStream_t stream) {
  const float* x = (const float*)d_in[0];
  const float* mask = (const float*)d_in[1];
  const float* niw = (const float*)d_in[2];
  const float* nib = (const float*)d_in[3];
  const float* p_in_w = (const float*)d_in[4];
  const float* g_in_w = (const float*)d_in[5];
  const float* now = (const float*)d_in[6];
  const float* nob = (const float*)d_in[7];
  const float* p_out_w = (const float*)d_in[8];
  const float* g_out_w = (const float*)d_in[9];
  float* out = (float*)d_out;
  char* ws = (char*)d_ws;

  // workspace layout (ws_size >= 268633088 proven on this harness, rounds 3-5)
  u16* At = (u16*)(ws);                   // 64 MiB
  u16* Bt = (u16*)(ws + 67108864);        // 64 MiB
  u16* Ct = (u16*)(ws + 134217728);       // 64 MiB
  u16* gA = (u16*)(ws + 201326592);       // 64 MiB
  u16* Wb = (u16*)(ws + 268435456);       // 128 KiB
  u16* Pb = (u16*)(ws + 268566528);       // 32 KiB
  u16* Gb = (u16*)(ws + 268599296);       // 32 KiB
  float* S12 = (float*)(ws + 268632064);  // 1 KiB

  hipLaunchKernelGGL(k0_prep, dim3(1), dim3(256), 0, stream, p_in_w, g_in_w,
                     p_out_w, g_out_w, now, nob, Wb, Pb, Gb, S12);
  hipLaunchKernelGGL(k1_ln_proj, dim3(4 * NROWS / 64), dim3(256), 0, stream, x,
                     mask, niw, nib, Wb, Gb, At, Bt, gA);
  hipLaunchKernelGGL(k2_tri, dim3(128 * 16), dim3(256), 0, stream, At, Bt, Ct);
  hipLaunchKernelGGL(k3_out, dim3(NROWS / 128), dim3(256), 0, stream, Ct, gA,
                     Pb, S12, out);
}

// Round 7
// 324.796 us; speedup vs baseline: 1.2902x; 1.2841x over previous
//
#include <hip/hip_runtime.h>
#include <stdint.h>

#define NSEQ 512
#define DDIM 128
#define NROWS (NSEQ * NSEQ)   // 262144

typedef __bf16 bf16x8 __attribute__((ext_vector_type(8)));
typedef __bf16 bf16x2v __attribute__((ext_vector_type(2)));
typedef unsigned short u16;
typedef u16 ushort8 __attribute__((ext_vector_type(8)));
typedef float f32x4 __attribute__((ext_vector_type(4)));
typedef uint32_t u32x4 __attribute__((ext_vector_type(4)));
typedef uint32_t u32x2 __attribute__((ext_vector_type(2)));

// native RNE converts (compiler emits v_cvt_f32->bf16 / v_cvt_pk_bf16_f32)
__device__ __forceinline__ u16 cvt1(float f) {
  return __builtin_bit_cast(u16, (__bf16)f);
}
__device__ __forceinline__ uint32_t pk2(float a, float b) {
  bf16x2v v = {(__bf16)a, (__bf16)b};
  return __builtin_bit_cast(uint32_t, v);
}
__device__ __forceinline__ float bf2f(u16 u) {
  uint32_t x = ((uint32_t)u) << 16;
  return __builtin_bit_cast(float, x);
}
__device__ __forceinline__ f32x4 mfma_bf16(ushort8 a, ushort8 b, f32x4 c) {
  return __builtin_amdgcn_mfma_f32_16x16x32_bf16(
      __builtin_bit_cast(bf16x8, a), __builtin_bit_cast(bf16x8, b), c, 0, 0, 0);
}
// sigmoid via v_exp + v_rcp (2 trans ops; rel err ~1e-7, far below bf16 ulp)
__device__ __forceinline__ float sigmoidf_(float x) {
  return __builtin_amdgcn_rcpf(1.0f + __expf(-x));
}

// DPP ROW_ROR rotate (within 16-lane rows), pure-VALU cross-lane
#define ROR16(v, n)                                                            \
  __builtin_bit_cast(float, __builtin_amdgcn_update_dpp(                       \
      __builtin_bit_cast(int, (v)), __builtin_bit_cast(int, (v)),              \
      0x120 + (n), 0xF, 0xF, false))

#define GLOAD16(gp, lp)                                                        \
  __builtin_amdgcn_global_load_lds(                                            \
      (const __attribute__((address_space(1))) void*)(gp),                     \
      (__attribute__((address_space(3))) void*)(lp), 16, 0, 0)

// ---------------------------------------------------------------------------
// K0: weight prep, parallelized across 128 blocks (was 1 block / serial).
// Block b: 512 Wb elems, 128 Pb/Gb elems, and S12[2b],S12[2b+1] (waves 2,3).
// ---------------------------------------------------------------------------
__global__ __launch_bounds__(256) void k0_prep(
    const float* __restrict__ p_in_w, const float* __restrict__ g_in_w,
    const float* __restrict__ p_out_w, const float* __restrict__ g_out_w,
    const float* __restrict__ now, const float* __restrict__ nob,
    u16* __restrict__ Wb, u16* __restrict__ Pb, u16* __restrict__ Gb,
    float* __restrict__ S12) {
  const int b = blockIdx.x, t = threadIdx.x;
#pragma unroll
  for (int k = 0; k < 2; ++k) {
    const int idx = b * 512 + k * 256 + t;  // [0, 65536)
    const float v = (idx < 32768) ? p_in_w[idx] : g_in_w[idx - 32768];
    Wb[idx] = cvt1(v);
  }
  if (t < 128) {
    const int idx = b * 128 + t;  // [0, 16384)
    const int d = idx & 127;
    Pb[idx] = cvt1(p_out_w[idx] * now[d]);
    Gb[idx] = cvt1(g_out_w[idx]);
  }
  const int w = t >> 6, lane = t & 63;
  if (w >= 2) {
    const float* wv = (w == 2) ? now : nob;
    float p = p_out_w[b * 128 + lane] * wv[lane] +
              p_out_w[b * 128 + 64 + lane] * wv[64 + lane];
#pragma unroll
    for (int m = 1; m < 64; m <<= 1) p += __shfl_xor(p, m);
    if (lane == 0) S12[2 * b + (w - 2)] = p;
  }
}

// ---------------------------------------------------------------------------
// K1 (structure = r6; LN reduce now DPP row_ror rotate-butterfly, sigmoid via
// rcp). 4-way column split, grid 16384.
// ---------------------------------------------------------------------------
__global__ __launch_bounds__(256, 6) void k1_ln_proj(
    const float* __restrict__ x, const float* __restrict__ mask,
    const float* __restrict__ niw, const float* __restrict__ nib,
    const u16* __restrict__ Wb, const u16* __restrict__ Gb,
    u16* __restrict__ At, u16* __restrict__ Bt, u16* __restrict__ gArg) {
  __shared__ __align__(16) u16 xln[64 * 128];   // 16KB, 16B-granule XOR swizzle
  __shared__ __align__(16) u16 stage[64 * 64];  // 8KB [d][r]; reused as stage2[r][e]
  const int tid = threadIdx.x;
  const int lane = tid & 63;
  const int w = tid >> 6;
  const int bid = blockIdx.x;
  const int rb = (bid >> 5) * 8 + (bid & 7);
  const int cg = (bid >> 3) & 3;
  const int r0 = rb * 64;
  const int g = lane >> 4, c = lane & 15;

  // --- LN phase: wave w rows [w*16, w*16+16), 4 rows/iter ---
  f32x4 v0[4], v1[4];
#pragma unroll
  for (int it = 0; it < 4; ++it) {
    const int rl = w * 16 + it * 4 + g;
    const float* xr = x + (size_t)(r0 + rl) * DDIM + c * 8;
    v0[it] = *(const f32x4*)xr;
    v1[it] = *(const f32x4*)(xr + 4);
  }
  const f32x4 w0 = *(const f32x4*)(niw + c * 8);
  const f32x4 w1 = *(const f32x4*)(niw + c * 8 + 4);
  const f32x4 b0 = *(const f32x4*)(nib + c * 8);
  const f32x4 b1 = *(const f32x4*)(nib + c * 8 + 4);
#pragma unroll
  for (int it = 0; it < 4; ++it) {
    const int rl = w * 16 + it * 4 + g;
    float s = v0[it][0] + v0[it][1] + v0[it][2] + v0[it][3] +
              v1[it][0] + v1[it][1] + v1[it][2] + v1[it][3];
    float ss = v0[it][0] * v0[it][0] + v0[it][1] * v0[it][1] +
               v0[it][2] * v0[it][2] + v0[it][3] * v0[it][3] +
               v1[it][0] * v1[it][0] + v1[it][1] * v1[it][1] +
               v1[it][2] * v1[it][2] + v1[it][3] * v1[it][3];
    // rotate-butterfly within the 16-lane row: all lanes end with full sum
    { float t1 = ROR16(s, 1); s += t1; t1 = ROR16(ss, 1); ss += t1; }
    { float t1 = ROR16(s, 2); s += t1; t1 = ROR16(ss, 2); ss += t1; }
    { float t1 = ROR16(s, 4); s += t1; t1 = ROR16(ss, 4); ss += t1; }
    { float t1 = ROR16(s, 8); s += t1; t1 = ROR16(ss, 8); ss += t1; }
    const float mu = s * (1.0f / 128.0f);
    const float rs = rsqrtf(ss * (1.0f / 128.0f) - mu * mu + 1e-5f);
    float f0 = (v0[it][0] - mu) * rs * w0[0] + b0[0];
    float f1 = (v0[it][1] - mu) * rs * w0[1] + b0[1];
    float f2 = (v0[it][2] - mu) * rs * w0[2] + b0[2];
    float f3 = (v0[it][3] - mu) * rs * w0[3] + b0[3];
    float f4 = (v1[it][0] - mu) * rs * w1[0] + b1[0];
    float f5 = (v1[it][1] - mu) * rs * w1[1] + b1[1];
    float f6 = (v1[it][2] - mu) * rs * w1[2] + b1[2];
    float f7 = (v1[it][3] - mu) * rs * w1[3] + b1[3];
    u32x4 ov{pk2(f0, f1), pk2(f2, f3), pk2(f4, f5), pk2(f6, f7)};
    const int byteoff = rl * 256 + ((c ^ (rl & 7)) << 4);
    *(u32x4*)((char*)xln + byteoff) = ov;
  }
  __syncthreads();

  // --- MFMA pass 1: wave w -> P col block eP..eP+16, G cols eP+256.. ---
  const int lr = lane & 15, lq = lane >> 4;
  const int eP = cg * 64 + w * 16;   // global P col base for this wave [0,256)
  f32x4 accP[4], accG[4];
#pragma unroll
  for (int m = 0; m < 4; ++m) {
    accP[m] = f32x4{0.f, 0.f, 0.f, 0.f};
    accG[m] = f32x4{0.f, 0.f, 0.f, 0.f};
  }

#pragma unroll
  for (int ks = 0; ks < 4; ++ks) {
    const int kblk = ks * 4 + lq;
    ushort8 af[4];
#pragma unroll
    for (int m = 0; m < 4; ++m) {
      const int row = m * 16 + lr;
      af[m] = *(const ushort8*)((const char*)xln + row * 256 +
                                ((kblk ^ (row & 7)) << 4));
    }
    const int e = eP + lr;
    const int dd = ks * 32 + lq * 8;
    const ushort8 bP = *(const ushort8*)(Wb + e * 128 + dd);
    const ushort8 bG = *(const ushort8*)(Wb + (256 + e) * 128 + dd);
#pragma unroll
    for (int m = 0; m < 4; ++m) {
      accP[m] = mfma_bf16(af[m], bP, accP[m]);
      accG[m] = mfma_bf16(af[m], bG, accG[m]);
    }
  }

  // --- epilogue: gate + mask -> swizzled LDS stage [d][r] (d in [0,64)) ---
  const int dloc = w * 16 + lr;  // col within this block's 64-col output
#pragma unroll
  for (int m = 0; m < 4; ++m) {
    const int rloc = m * 16 + lq * 4;
    const f32x4 mv = *(const f32x4*)(mask + r0 + rloc);
    const float o0 = accP[m][0] * sigmoidf_(accG[m][0]) * mv[0];
    const float o1 = accP[m][1] * sigmoidf_(accG[m][1]) * mv[1];
    const float o2 = accP[m][2] * sigmoidf_(accG[m][2]) * mv[2];
    const float o3 = accP[m][3] * sigmoidf_(accG[m][3]) * mv[3];
    u32x2 pk;
    pk[0] = pk2(o0, o1);
    pk[1] = pk2(o2, o3);
    const int gsw = (m * 4 + lq) ^ (dloc & 15);  // 8B granule XOR swizzle
    *(u32x2*)((char*)stage + dloc * 128 + (gsw << 3)) = pk;
  }
  __syncthreads();

  // --- write phase: full 64B-line coalesced stores (2 per thread) ---
  {
    u16* dstbase = (cg >= 2) ? Bt : At;
    const int colbase = (cg & 1) * 64;
    const int R = tid >> 1;            // region [0,128)
    const int dl = R >> 1, seg = R & 1;
#pragma unroll
    for (int rr = 0; rr < 2; ++rr) {
      const int il = (tid & 1) * 2 + rr;  // [0,4)
      const int g0 = seg * 8 + il * 2;    // logical 8B granule
      const u32x2 lo =
          *(const u32x2*)((const char*)stage + dl * 128 + ((g0 ^ (dl & 15)) << 3));
      const u32x2 hi = *(const u32x2*)((const char*)stage + dl * 128 +
                                       (((g0 + 1) ^ (dl & 15)) << 3));
      u32x4 outv{lo[0], lo[1], hi[0], hi[1]};
      *(u32x4*)(dstbase + (size_t)(colbase + dl) * NROWS + r0 + seg * 32 +
                il * 8) = outv;
    }
  }

  // --- MFMA pass 2 (cg 0,1 only; verified layout): gArg = xln @ g_out^T ---
  if (cg < 2) {
    f32x4 accO[4];
#pragma unroll
    for (int m = 0; m < 4; ++m) accO[m] = f32x4{0.f, 0.f, 0.f, 0.f};
    const int eg = cg * 64 + w * 16 + lr;
#pragma unroll
    for (int ks = 0; ks < 4; ++ks) {
      const int kblk = ks * 4 + lq;
      const ushort8 bO = *(const ushort8*)(Gb + eg * 128 + ks * 32 + lq * 8);
#pragma unroll
      for (int m = 0; m < 4; ++m) {
        const int row = m * 16 + lr;
        const ushort8 af2 = *(const ushort8*)((const char*)xln + row * 256 +
                                              ((kblk ^ (row & 7)) << 4));
        accO[m] = mfma_bf16(af2, bO, accO[m]);
      }
    }
    __syncthreads();  // all threads done reading `stage` -> safe to alias
    // stage2[r_loc][e_loc] (2B LDS writes, 8B-granule XOR swizzle)
    u16* stage2 = stage;
    const int e_loc = w * 16 + lr;        // [0,64)
    const int gsl = e_loc >> 2;           // logical 8B granule [0,16)
    const int esub = (e_loc & 3) * 2;     // byte within granule
#pragma unroll
    for (int m = 0; m < 4; ++m) {
#pragma unroll
      for (int reg = 0; reg < 4; ++reg) {
        const int rl2 = m * 16 + lq * 4 + reg;
        *(u16*)((char*)stage2 + rl2 * 128 + ((gsl ^ (rl2 & 7)) << 3) + esub) =
            cvt1(accO[m][reg]);
      }
    }
    __syncthreads();
    // read-back: 16B coalesced stores, 8 threads cover one 128B row
#pragma unroll
    for (int p = 0; p < 2; ++p) {
      const int r = p * 32 + (tid >> 3);
      const int il8 = tid & 7;
      const char* base = (const char*)stage2 + r * 128;
      const u32x2 a = *(const u32x2*)(base + (((il8 * 2) ^ (r & 7)) << 3));
      const u32x2 b = *(const u32x2*)(base + (((il8 * 2 + 1) ^ (r & 7)) << 3));
      u32x4 ov{a[0], a[1], b[0], b[1]};
      *(u32x4*)(gArg + (size_t)(r0 + r) * DDIM + cg * 64 + il8 * 8) = ov;
    }
  }
}

// ---------------------------------------------------------------------------
// K2: per-d GEMM  t[i][j][d] = sum_k a[i][k][d] * b[j][k][d]   (unchanged)
// ---------------------------------------------------------------------------
__global__ __launch_bounds__(256) void k2_tri(const u16* __restrict__ At,
                                              const u16* __restrict__ Bt,
                                              u16* __restrict__ Ct) {
  __shared__ __align__(16) u16 lds[2 * 16384];  // [buf][A:8192 | B:8192] elems
  const int tid = threadIdx.x;
  const int bid = blockIdx.x;
  const int lb = (bid & 7) * 256 + (bid >> 3);
  const int d = lb >> 4;
  const int tile = lb & 15;
  const int i0 = (tile >> 2) * 128, j0 = (tile & 3) * 128;
  const u16* Ad = At + (size_t)d * NROWS;
  const u16* Bd = Bt + (size_t)d * NROWS;
  const int lane = tid & 63, wid = tid >> 6;
  const int wr = wid >> 1, wc = wid & 1;
  const int lr = lane & 15, lq = lane >> 4;

  f32x4 acc[4][4];
#pragma unroll
  for (int m = 0; m < 4; ++m)
#pragma unroll
    for (int n = 0; n < 4; ++n) acc[m][n] = f32x4{0.f, 0.f, 0.f, 0.f};

  auto stage = [&](int kt, int buf) {
    const int k0 = kt * 64;
#pragma unroll
    for (int q = 0; q < 4; ++q) {
      const int idx = q * 256 + tid;  // 0..1023
      const int r = idx >> 3, bk = idx & 7;
      const int sbk = bk ^ (r & 7);  // pre-swizzled global source
      GLOAD16(Ad + (size_t)(i0 + r) * NSEQ + k0 + sbk * 8,
              &lds[buf * 16384 + idx * 8]);
      GLOAD16(Bd + (size_t)(j0 + r) * NSEQ + k0 + sbk * 8,
              &lds[buf * 16384 + 8192 + idx * 8]);
    }
  };

  stage(0, 0);
  __syncthreads();
  for (int kt = 0; kt < 8; ++kt) {
    const int buf = kt & 1;
    if (kt < 7) stage(kt + 1, buf ^ 1);
    const u16* A_l = &lds[buf * 16384];
    const u16* B_l = &lds[buf * 16384 + 8192];
#pragma unroll
    for (int ks = 0; ks < 2; ++ks) {
      const int kblk = ks * 4 + lq;
      ushort8 af[4], bfr[4];
#pragma unroll
      for (int m = 0; m < 4; ++m) {
        const int row = wr * 64 + m * 16 + lr;
        af[m] = *(const ushort8*)((const char*)A_l + row * 128 +
                                  ((kblk ^ (row & 7)) << 4));
      }
#pragma unroll
      for (int n = 0; n < 4; ++n) {
        const int col = wc * 64 + n * 16 + lr;
        bfr[n] = *(const ushort8*)((const char*)B_l + col * 128 +
                                   ((kblk ^ (col & 7)) << 4));
      }
#pragma unroll
      for (int m = 0; m < 4; ++m)
#pragma unroll
        for (int n = 0; n < 4; ++n)
          acc[m][n] = mfma_bf16(af[m], bfr[n], acc[m][n]);
    }
    __syncthreads();
  }

  u16* Cd = Ct + (size_t)d * NROWS;
#pragma unroll
  for (int m = 0; m < 4; ++m) {
    const int i = i0 + wr * 64 + m * 16 + lq * 4;
#pragma unroll
    for (int n = 0; n < 4; ++n) {
      const int j = j0 + wc * 64 + n * 16 + lr;
#pragma unroll
      for (int reg = 0; reg < 4; ++reg)
        Cd[(size_t)(i + reg) * NSEQ + j] = cvt1(acc[m][n][reg]);
    }
  }
}

// ---------------------------------------------------------------------------
// K3: out = (rs*(T@P'^T)+affine)*sigmoid(gArg)   (r6 structure, fast sigmoid)
// ---------------------------------------------------------------------------
__global__ __launch_bounds__(256, 4) void k3_out(
    const u16* __restrict__ Ct, const u16* __restrict__ gArg,
    const u16* __restrict__ Pb, const float* __restrict__ S12,
    float* __restrict__ out) {
  __shared__ __align__(16) u16 ldsT[128 * 128];  // [r][d], 16B XOR swizzle
  __shared__ float ps[4 * 128], pss[4 * 128];
  __shared__ float prm[128 * 2];
  __shared__ float s12l[128 * 2];
  const int tid = threadIdx.x, lane = tid & 63, w = tid >> 6;
  const int c0 = blockIdx.x * 128;

  // --- phase A: all 4 waves stream Ct columns; wave w = d-quarter w ---
  {
    const int row2 = lane * 2;  // rows row2, row2+1
    const u16* cp = Ct + c0 + row2;
    float s0 = 0.f, ss0 = 0.f, s1 = 0.f, ss1 = 0.f;
#pragma unroll
    for (int db = 0; db < 4; ++db) {
      uint32_t pe[4], po[4];
#pragma unroll
      for (int j = 0; j < 8; ++j) {
        const int d = w * 32 + db * 8 + j;
        const uint32_t v = *(const uint32_t*)(cp + (size_t)d * NROWS);
        const u16 ue = (u16)v, uo = (u16)(v >> 16);
        const float fe = bf2f(ue), fo = bf2f(uo);
        s0 += fe; ss0 += fe * fe;
        s1 += fo; ss1 += fo * fo;
        if (j & 1) {
          pe[j >> 1] |= ((uint32_t)ue) << 16;
          po[j >> 1] |= ((uint32_t)uo) << 16;
        } else {
          pe[j >> 1] = ue;
          po[j >> 1] = uo;
        }
      }
      const int gr = w * 4 + db;  // granule 0..15 (8 d's each)
      *(u32x4*)((char*)ldsT + row2 * 256 + ((gr ^ (row2 & 7)) << 4)) =
          u32x4{pe[0], pe[1], pe[2], pe[3]};
      *(u32x4*)((char*)ldsT + (row2 + 1) * 256 + ((gr ^ ((row2 + 1) & 7)) << 4)) =
          u32x4{po[0], po[1], po[2], po[3]};
    }
    ps[w * 128 + row2] = s0;
    pss[w * 128 + row2] = ss0;
    ps[w * 128 + row2 + 1] = s1;
    pss[w * 128 + row2 + 1] = ss1;
  }
  if (tid < 128) ((u32x2*)s12l)[tid] = ((const u32x2*)S12)[tid];
  __syncthreads();
  if (tid < 128) {
    const float s = ps[tid] + ps[128 + tid] + ps[256 + tid] + ps[384 + tid];
    const float ss = pss[tid] + pss[128 + tid] + pss[256 + tid] + pss[384 + tid];
    const float mu = s * (1.f / 128.f);
    const float rs = rsqrtf(ss * (1.f / 128.f) - mu * mu + 1e-5f);
    prm[2 * tid] = rs;
    prm[2 * tid + 1] = -rs * mu;
  }

  // --- MFMA: wave w owns rows [w*32, w*32+32), all 128 e cols ---
  const int lr = lane & 15, lq = lane >> 4;
  const int rowbase = w * 32;
  f32x4 aP[2][8];
#pragma unroll
  for (int m = 0; m < 2; ++m)
#pragma unroll
    for (int n = 0; n < 8; ++n) aP[m][n] = f32x4{0.f, 0.f, 0.f, 0.f};
#pragma unroll
  for (int ks = 0; ks < 4; ++ks) {
    const int kblk = ks * 4 + lq;
    ushort8 at2[2];
#pragma unroll
    for (int m = 0; m < 2; ++m) {
      const int row = rowbase + m * 16 + lr;
      at2[m] = *(const ushort8*)((const char*)ldsT + row * 256 +
                                 ((kblk ^ (row & 7)) << 4));
    }
    ushort8 bp[8];
#pragma unroll
    for (int n = 0; n < 8; ++n) {
      const int e = n * 16 + lr;
      bp[n] = *(const ushort8*)(Pb + e * 128 + ks * 32 + lq * 8);
    }
#pragma unroll
    for (int m = 0; m < 2; ++m)
#pragma unroll
      for (int n = 0; n < 8; ++n) aP[m][n] = mfma_bf16(at2[m], bp[n], aP[m][n]);
  }
  __syncthreads();  // prm/s12l ready for epilogue

  // --- epilogue ---
#pragma unroll
  for (int m = 0; m < 2; ++m) {
    const int crow = rowbase + m * 16 + lq * 4;
#pragma unroll
    for (int n = 0; n < 8; ++n) {
      const int e = n * 16 + lr;
      const float s1 = s12l[2 * e], s2v = s12l[2 * e + 1];
#pragma unroll
      for (int reg = 0; reg < 4; ++reg) {
        const float rs = prm[2 * (crow + reg)];
        const float t1 = prm[2 * (crow + reg) + 1];
        const float op = rs * aP[m][n][reg] + t1 * s1 + s2v;
        const size_t r = (size_t)(c0 + crow + reg);
        const float gt = sigmoidf_(bf2f(gArg[r * DDIM + e]));
        out[r * DDIM + e] = op * gt;
      }
    }
  }
}

// ---------------------------------------------------------------------------
extern "C" void kernel_launch(void* const* d_in, const int* in_sizes, int n_in,
                              void* d_out, int out_size, void* d_ws,
                              size_t ws_size, hipStream_t stream) {
  const float* x = (const float*)d_in[0];
  const float* mask = (const float*)d_in[1];
  const float* niw = (const float*)d_in[2];
  const float* nib = (const float*)d_in[3];
  const float* p_in_w = (const float*)d_in[4];
  const float* g_in_w = (const float*)d_in[5];
  const float* now = (const float*)d_in[6];
  const float* nob = (const float*)d_in[7];
  const float* p_out_w = (const float*)d_in[8];
  const float* g_out_w = (const float*)d_in[9];
  float* out = (float*)d_out;
  char* ws = (char*)d_ws;

  // workspace layout (ws_size >= 268633088 proven on this harness, rounds 3-6)
  u16* At = (u16*)(ws);                   // 64 MiB
  u16* Bt = (u16*)(ws + 67108864);        // 64 MiB
  u16* Ct = (u16*)(ws + 134217728);       // 64 MiB
  u16* gA = (u16*)(ws + 201326592);       // 64 MiB
  u16* Wb = (u16*)(ws + 268435456);       // 128 KiB
  u16* Pb = (u16*)(ws + 268566528);       // 32 KiB
  u16* Gb = (u16*)(ws + 268599296);       // 32 KiB
  float* S12 = (float*)(ws + 268632064);  // 1 KiB

  hipLaunchKernelGGL(k0_prep, dim3(128), dim3(256), 0, stream, p_in_w, g_in_w,
                     p_out_w, g_out_w, now, nob, Wb, Pb, Gb, S12);
  hipLaunchKernelGGL(k1_ln_proj, dim3(4 * NROWS / 64), dim3(256), 0, stream, x,
                     mask, niw, nib, Wb, Gb, At, Bt, gA);
  hipLaunchKernelGGL(k2_tri, dim3(128 * 16), dim3(256), 0, stream, At, Bt, Ct);
  hipLaunchKernelGGL(k3_out, dim3(NROWS / 128), dim3(256), 0, stream, Ct, gA,
                     Pb, S12, out);
}